// Round 1
// baseline (924.037 us; speedup 1.0000x reference)
//
#include <hip/hip_runtime.h>

#define N_NODES 50000
#define N_EDGES 800000
#define D_IN 128
#define HIDDEN 64
#define N_CLASSES 2

// ---------------- degree / dinv ----------------

__global__ __launch_bounds__(256) void k_init_deg(float* deg) {
    int i = blockIdx.x * 256 + threadIdx.x;
    if (i < N_NODES) deg[i] = 1.0f;  // self-loop
}

__global__ __launch_bounds__(256) void k_count_deg(const int* __restrict__ dst, float* deg) {
    int e = blockIdx.x * 256 + threadIdx.x;
    if (e < N_EDGES) atomicAdd(&deg[dst[e]], 1.0f);
}

__global__ __launch_bounds__(256) void k_dinv(float* deg) {
    int i = blockIdx.x * 256 + threadIdx.x;
    if (i < N_NODES) deg[i] = rsqrtf(deg[i]);  // deg >= 1 always (self-loop)
}

// ---------------- GEMM1: h = x @ W1 ; agg1 = h * dinv^2 (self-loop init) ----------------

__device__ inline void fma4(float4& acc, float s, const float4& w) {
    acc.x = fmaf(s, w.x, acc.x);
    acc.y = fmaf(s, w.y, acc.y);
    acc.z = fmaf(s, w.z, acc.z);
    acc.w = fmaf(s, w.w, acc.w);
}

// block 256, tile: 64 rows x 64 cols, K=128 fully resident.
// LDS 64KB total -> 2 blocks/CU. Per-thread 4 rows x 4 cols.
// xs is XOR-swizzled: row r, k-chunk swizzle (((r>>2)&1)<<4) -> 2-way-max bank
// aliasing on the a-reads (free per m136), conflict-free staging writes.
__global__ __launch_bounds__(256) void k_gemm1(
    const float* __restrict__ x, const float* __restrict__ W1,
    const float* __restrict__ dinv, float* __restrict__ h, float* __restrict__ agg1)
{
    __shared__ float Ws[D_IN * HIDDEN];  // [k][col] 32KB
    __shared__ float xs[64 * D_IN];      // [row][k^swz] 32KB
    const int tid = threadIdx.x;
    const int row0 = blockIdx.x * 64;

    // stage W1 (coalesced float4)
    const float4* W4 = (const float4*)W1;
    float4* Ws4 = (float4*)Ws;
    for (int i = tid; i < D_IN * HIDDEN / 4; i += 256) Ws4[i] = W4[i];

    // stage x tile (coalesced global float4, swizzled LDS write)
    for (int i = tid; i < 64 * D_IN / 4; i += 256) {
        int r = i >> 5;            // 32 float4 per row
        int k4 = (i & 31) << 2;    // k offset
        float4 v = make_float4(0.f, 0.f, 0.f, 0.f);
        int grow = row0 + r;
        if (grow < N_NODES) v = *(const float4*)&x[grow * D_IN + k4];
        int sw = ((r >> 2) & 1) << 4;
        *(float4*)&xs[r * D_IN + (k4 ^ sw)] = v;
    }
    __syncthreads();

    const int c4 = (tid & 15) * 4;
    const int r4 = (tid >> 4) * 4;
    float4 acc[4];
#pragma unroll
    for (int j = 0; j < 4; j++) acc[j] = make_float4(0.f, 0.f, 0.f, 0.f);

    for (int k = 0; k < D_IN; k += 4) {
        float4 w0 = *(const float4*)&Ws[(k + 0) * HIDDEN + c4];
        float4 w1 = *(const float4*)&Ws[(k + 1) * HIDDEN + c4];
        float4 w2 = *(const float4*)&Ws[(k + 2) * HIDDEN + c4];
        float4 w3 = *(const float4*)&Ws[(k + 3) * HIDDEN + c4];
        float4 a[4];
#pragma unroll
        for (int j = 0; j < 4; j++) {
            int r = r4 + j;
            int sw = ((r >> 2) & 1) << 4;
            a[j] = *(const float4*)&xs[r * D_IN + (k ^ sw)];
        }
#pragma unroll
        for (int j = 0; j < 4; j++) {
            fma4(acc[j], a[j].x, w0);
            fma4(acc[j], a[j].y, w1);
            fma4(acc[j], a[j].z, w2);
            fma4(acc[j], a[j].w, w3);
        }
    }

#pragma unroll
    for (int j = 0; j < 4; j++) {
        int grow = row0 + r4 + j;
        if (grow < N_NODES) {
            *(float4*)&h[grow * HIDDEN + c4] = acc[j];
            float di = dinv[grow];
            float s = di * di;
            float4 t = acc[j];
            t.x *= s; t.y *= s; t.z *= s; t.w *= s;
            *(float4*)&agg1[grow * HIDDEN + c4] = t;
        }
    }
}

// ---------------- edge aggregation, layer 1 (push / atomics) ----------------
// 16 threads per edge, float4 gather, 4 scalar atomics each.
__global__ __launch_bounds__(256) void k_agg1(
    const int* __restrict__ src, const int* __restrict__ dst,
    const float* __restrict__ dinv, const float* __restrict__ h,
    float* __restrict__ agg1)
{
    int gi = blockIdx.x * 256 + threadIdx.x;   // E*16 = 12.8M, exact grid
    int e = gi >> 4;
    int part = gi & 15;
    int s = src[e];
    int d = dst[e];
    float w = dinv[s] * dinv[d];
    float4 v = *(const float4*)&h[s * HIDDEN + part * 4];
    float* o = &agg1[d * HIDDEN + part * 4];
    atomicAdd(o + 0, v.x * w);
    atomicAdd(o + 1, v.y * w);
    atomicAdd(o + 2, v.z * w);
    atomicAdd(o + 3, v.w * w);
}

// ---------------- layer 2: relu(agg1+b1) @ W2 ; init out with self-loop + b2 ----------------
// one wave per node (64 lanes == HIDDEN), wave-reduce for the 2 output classes.
__global__ __launch_bounds__(256) void k_layer2(
    const float* __restrict__ agg1, const float* __restrict__ b1,
    const float* __restrict__ W2, const float* __restrict__ b2,
    const float* __restrict__ dinv, float* __restrict__ z, float* __restrict__ out)
{
    int node = blockIdx.x * 4 + (threadIdx.x >> 6);   // grid 12500, exact
    int lane = threadIdx.x & 63;
    float a = agg1[node * HIDDEN + lane] + b1[lane];
    float y = fmaxf(a, 0.0f);
    float p0 = y * W2[lane * N_CLASSES + 0];
    float p1 = y * W2[lane * N_CLASSES + 1];
#pragma unroll
    for (int off = 32; off > 0; off >>= 1) {
        p0 += __shfl_down(p0, off, 64);
        p1 += __shfl_down(p1, off, 64);
    }
    if (lane == 0) {
        float di = dinv[node];
        float s2 = di * di;
        z[node * 2 + 0] = p0;
        z[node * 2 + 1] = p1;
        out[node * 2 + 0] = fmaf(p0, s2, b2[0]);
        out[node * 2 + 1] = fmaf(p1, s2, b2[1]);
    }
}

// ---------------- edge aggregation, layer 2 ----------------
__global__ __launch_bounds__(256) void k_agg2(
    const int* __restrict__ src, const int* __restrict__ dst,
    const float* __restrict__ dinv, const float* __restrict__ z,
    float* __restrict__ out)
{
    int e = blockIdx.x * 256 + threadIdx.x;  // grid 3125, exact
    int s = src[e];
    int d = dst[e];
    float w = dinv[s] * dinv[d];
    float2 v = *(const float2*)&z[s * 2];
    atomicAdd(&out[d * 2 + 0], v.x * w);
    atomicAdd(&out[d * 2 + 1], v.y * w);
}

// ---------------- launch ----------------

extern "C" void kernel_launch(void* const* d_in, const int* in_sizes, int n_in,
                              void* d_out, int out_size, void* d_ws, size_t ws_size,
                              hipStream_t stream) {
    const float* x  = (const float*)d_in[0];
    const int* ei   = (const int*)d_in[1];
    const float* W1 = (const float*)d_in[2];
    const float* b1 = (const float*)d_in[3];
    const float* W2 = (const float*)d_in[4];
    const float* b2 = (const float*)d_in[5];
    float* out = (float*)d_out;

    const int* src = ei;             // edge_index[0]
    const int* dst = ei + N_EDGES;   // edge_index[1]

    // workspace layout (floats): dinv | h | agg1 | z  (~26.2 MB total)
    float* ws   = (float*)d_ws;
    float* deg  = ws;                     // 50048 (deg -> dinv in place)
    float* h    = ws + 50048;             // 3,200,000 (16B aligned)
    float* agg1 = h + (size_t)N_NODES * HIDDEN;   // 3,200,000
    float* z    = agg1 + (size_t)N_NODES * HIDDEN; // 100,000

    k_init_deg<<<(N_NODES + 255) / 256, 256, 0, stream>>>(deg);
    k_count_deg<<<(N_EDGES + 255) / 256, 256, 0, stream>>>(dst, deg);
    k_dinv<<<(N_NODES + 255) / 256, 256, 0, stream>>>(deg);
    k_gemm1<<<(N_NODES + 63) / 64, 256, 0, stream>>>(x, W1, deg, h, agg1);
    k_agg1<<<(N_EDGES * 16) / 256, 256, 0, stream>>>(src, dst, deg, h, agg1);
    k_layer2<<<N_NODES / 4, 256, 0, stream>>>(agg1, b1, W2, b2, deg, z, out);
    k_agg2<<<N_EDGES / 256, 256, 0, stream>>>(src, dst, deg, z, out);
}

// Round 2
// 361.869 us; speedup vs baseline: 2.5535x; 2.5535x over previous
//
#include <hip/hip_runtime.h>

#define N_NODES 50000
#define N_EDGES 800000
#define D_IN 128
#define HIDDEN 64
#define N_CLASSES 2
#define NPAD 50176  // 196*256, padded node count for the scan

// ---------------- degree count (int) ----------------

__global__ __launch_bounds__(256) void k_count_deg(const int* __restrict__ dst, int* degc) {
    int e = blockIdx.x * 256 + threadIdx.x;
    if (e < N_EDGES) atomicAdd(&degc[dst[e]], 1);
}

// ---------------- single-block exclusive scan -> row_ptr, cursor ----------------
// 256 threads, each owns a 196-element segment. ~200KB r/w, one-off cost.
__global__ __launch_bounds__(256) void k_scan(const int* __restrict__ degc,
                                              int* __restrict__ row_ptr,
                                              int* __restrict__ cursor) {
    __shared__ int part[256];
    const int SEG = 196;
    int t = threadIdx.x;
    int beg = t * SEG;
    int end = beg + SEG < N_NODES ? beg + SEG : N_NODES;
    int s = 0;
    for (int i = beg; i < end; i++) s += degc[i];
    part[t] = s;
    __syncthreads();
    // inclusive Hillis-Steele scan of the 256 partials
    for (int off = 1; off < 256; off <<= 1) {
        int v = (t >= off) ? part[t - off] : 0;
        __syncthreads();
        if (t >= off) part[t] += v;
        __syncthreads();
    }
    int run = (t == 0) ? 0 : part[t - 1];
    for (int i = beg; i < end; i++) {
        row_ptr[i] = run;
        cursor[i] = run;
        run += degc[i];
    }
    if (t == 255) row_ptr[N_NODES] = run;  // == N_EDGES
}

// ---------------- dinv ----------------

__global__ __launch_bounds__(256) void k_dinv(const int* __restrict__ degc, float* dinv) {
    int i = blockIdx.x * 256 + threadIdx.x;
    if (i < N_NODES) dinv[i] = rsqrtf((float)(degc[i] + 1));  // +1 self-loop
}

// ---------------- scatter edges into CSR records (src, w) ----------------

__global__ __launch_bounds__(256) void k_scatter(const int* __restrict__ src,
                                                 const int* __restrict__ dst,
                                                 const float* __restrict__ dinv,
                                                 int* __restrict__ cursor,
                                                 int2* __restrict__ rec) {
    int e = blockIdx.x * 256 + threadIdx.x;
    if (e >= N_EDGES) return;
    int s = src[e];
    int d = dst[e];
    float w = dinv[s] * dinv[d];
    int pos = atomicAdd(&cursor[d], 1);
    rec[pos] = make_int2(s, __float_as_int(w));
}

// ---------------- GEMM1: h = x @ W1 ----------------

__device__ inline void fma4(float4& acc, float s, const float4& w) {
    acc.x = fmaf(s, w.x, acc.x);
    acc.y = fmaf(s, w.y, acc.y);
    acc.z = fmaf(s, w.z, acc.z);
    acc.w = fmaf(s, w.w, acc.w);
}

__global__ __launch_bounds__(256) void k_gemm1(
    const float* __restrict__ x, const float* __restrict__ W1, float* __restrict__ h)
{
    __shared__ float Ws[D_IN * HIDDEN];  // [k][col] 32KB
    __shared__ float xs[64 * D_IN];      // [row][k^swz] 32KB
    const int tid = threadIdx.x;
    const int row0 = blockIdx.x * 64;

    const float4* W4 = (const float4*)W1;
    float4* Ws4 = (float4*)Ws;
    for (int i = tid; i < D_IN * HIDDEN / 4; i += 256) Ws4[i] = W4[i];

    for (int i = tid; i < 64 * D_IN / 4; i += 256) {
        int r = i >> 5;
        int k4 = (i & 31) << 2;
        float4 v = make_float4(0.f, 0.f, 0.f, 0.f);
        int grow = row0 + r;
        if (grow < N_NODES) v = *(const float4*)&x[grow * D_IN + k4];
        int sw = ((r >> 2) & 1) << 4;
        *(float4*)&xs[r * D_IN + (k4 ^ sw)] = v;
    }
    __syncthreads();

    const int c4 = (tid & 15) * 4;
    const int r4 = (tid >> 4) * 4;
    float4 acc[4];
#pragma unroll
    for (int j = 0; j < 4; j++) acc[j] = make_float4(0.f, 0.f, 0.f, 0.f);

    for (int k = 0; k < D_IN; k += 4) {
        float4 w0 = *(const float4*)&Ws[(k + 0) * HIDDEN + c4];
        float4 w1 = *(const float4*)&Ws[(k + 1) * HIDDEN + c4];
        float4 w2 = *(const float4*)&Ws[(k + 2) * HIDDEN + c4];
        float4 w3 = *(const float4*)&Ws[(k + 3) * HIDDEN + c4];
        float4 a[4];
#pragma unroll
        for (int j = 0; j < 4; j++) {
            int r = r4 + j;
            int sw = ((r >> 2) & 1) << 4;
            a[j] = *(const float4*)&xs[r * D_IN + (k ^ sw)];
        }
#pragma unroll
        for (int j = 0; j < 4; j++) {
            fma4(acc[j], a[j].x, w0);
            fma4(acc[j], a[j].y, w1);
            fma4(acc[j], a[j].z, w2);
            fma4(acc[j], a[j].w, w3);
        }
    }

#pragma unroll
    for (int j = 0; j < 4; j++) {
        int grow = row0 + r4 + j;
        if (grow < N_NODES) *(float4*)&h[grow * HIDDEN + c4] = acc[j];
    }
}

// ---------------- fused: pull-aggregate layer1 + relu + layer2 matmul + self-loop init ----------------
// one wave per node; lane = feature. Per edge: 8B broadcast record + 256B coalesced h-row.
__global__ __launch_bounds__(256) void k_agg1_l2(
    const float* __restrict__ h, const int* __restrict__ row_ptr,
    const int2* __restrict__ rec, const float* __restrict__ dinv,
    const float* __restrict__ b1, const float* __restrict__ W2,
    const float* __restrict__ b2, float* __restrict__ z, float* __restrict__ out)
{
    int node = blockIdx.x * 4 + (threadIdx.x >> 6);  // grid 12500, exact
    int lane = threadIdx.x & 63;

    float di = dinv[node];
    float acc = h[node * HIDDEN + lane] * (di * di);  // self-loop term

    int beg = row_ptr[node];
    int end = row_ptr[node + 1];
    int e = beg;
    // 2-edge software pipeline to keep two h-row loads in flight
    for (; e + 1 < end; e += 2) {
        int2 r0 = rec[e];
        int2 r1 = rec[e + 1];
        float v0 = h[(size_t)r0.x * HIDDEN + lane];
        float v1 = h[(size_t)r1.x * HIDDEN + lane];
        acc = fmaf(v0, __int_as_float(r0.y), acc);
        acc = fmaf(v1, __int_as_float(r1.y), acc);
    }
    if (e < end) {
        int2 r0 = rec[e];
        acc = fmaf(h[(size_t)r0.x * HIDDEN + lane], __int_as_float(r0.y), acc);
    }

    // layer 2: y = relu(acc + b1); p = y @ W2 (wave-reduce)
    float y = fmaxf(acc + b1[lane], 0.0f);
    float p0 = y * W2[lane * N_CLASSES + 0];
    float p1 = y * W2[lane * N_CLASSES + 1];
#pragma unroll
    for (int off = 32; off > 0; off >>= 1) {
        p0 += __shfl_down(p0, off, 64);
        p1 += __shfl_down(p1, off, 64);
    }
    if (lane == 0) {
        float s2 = di * di;
        z[node * 2 + 0] = p0;
        z[node * 2 + 1] = p1;
        out[node * 2 + 0] = fmaf(p0, s2, b2[0]);  // self-loop + bias init
        out[node * 2 + 1] = fmaf(p1, s2, b2[1]);
    }
}

// ---------------- pull-aggregate layer 2 (thread per node) ----------------

__global__ __launch_bounds__(256) void k_agg2(
    const float* __restrict__ z, const int* __restrict__ row_ptr,
    const int2* __restrict__ rec, float* __restrict__ out)
{
    int i = blockIdx.x * 256 + threadIdx.x;
    if (i >= N_NODES) return;
    float a0 = out[i * 2 + 0];
    float a1 = out[i * 2 + 1];
    int beg = row_ptr[i];
    int end = row_ptr[i + 1];
    for (int e = beg; e < end; e++) {
        int2 r = rec[e];
        float w = __int_as_float(r.y);
        float2 v = *(const float2*)&z[r.x * 2];
        a0 = fmaf(v.x, w, a0);
        a1 = fmaf(v.y, w, a1);
    }
    out[i * 2 + 0] = a0;
    out[i * 2 + 1] = a1;
}

// ---------------- launch ----------------

extern "C" void kernel_launch(void* const* d_in, const int* in_sizes, int n_in,
                              void* d_out, int out_size, void* d_ws, size_t ws_size,
                              hipStream_t stream) {
    const float* x  = (const float*)d_in[0];
    const int* ei   = (const int*)d_in[1];
    const float* W1 = (const float*)d_in[2];
    const float* b1 = (const float*)d_in[3];
    const float* W2 = (const float*)d_in[4];
    const float* b2 = (const float*)d_in[5];
    float* out = (float*)d_out;

    const int* src = ei;
    const int* dst = ei + N_EDGES;

    // workspace layout (4-byte units)
    int*   degc    = (int*)d_ws;                     // [0, 50176)
    float* dinv    = (float*)d_ws + NPAD;            // [50176, 100352)
    int*   row_ptr = (int*)d_ws + 2 * NPAD;          // [100352, 150529) -> pad to 150532
    int*   cursor  = (int*)d_ws + 150532;            // [150532, 200708)
    int2*  rec     = (int2*)((int*)d_ws + 200708);   // 800000 int2 = 1.6M units
    float* h       = (float*)d_ws + 1800708;         // 3.2M units (16B aligned)
    float* z       = (float*)d_ws + 5000708;         // 100k units

    hipMemsetAsync(degc, 0, NPAD * sizeof(int), stream);
    k_count_deg<<<(N_EDGES + 255) / 256, 256, 0, stream>>>(dst, degc);
    k_scan<<<1, 256, 0, stream>>>(degc, row_ptr, cursor);
    k_dinv<<<(N_NODES + 255) / 256, 256, 0, stream>>>(degc, dinv);
    k_scatter<<<(N_EDGES + 255) / 256, 256, 0, stream>>>(src, dst, dinv, cursor, rec);
    k_gemm1<<<(N_NODES + 63) / 64, 256, 0, stream>>>(x, W1, h);
    k_agg1_l2<<<N_NODES / 4, 256, 0, stream>>>(h, row_ptr, rec, dinv, b1, W2, b2, z, out);
    k_agg2<<<(N_NODES + 255) / 256, 256, 0, stream>>>(z, row_ptr, rec, out);
}

// Round 3
// 251.856 us; speedup vs baseline: 3.6689x; 1.4368x over previous
//
#include <hip/hip_runtime.h>

#define N_NODES 50000
#define N_EDGES 800000
#define D_IN 128
#define HIDDEN 64
#define N_CLASSES 2
#define NB 196          // scan blocks: 196*256 = 50176 >= N_NODES
#define NPAD 50176

// ---------------- degree count (int) ----------------

__global__ __launch_bounds__(256) void k_count_deg(const int* __restrict__ dst, int* degc) {
    int e = blockIdx.x * 256 + threadIdx.x;
    if (e < N_EDGES) atomicAdd(&degc[dst[e]], 1);
}

// ---------------- parallel scan, phase 1: per-block sums ----------------

__global__ __launch_bounds__(256) void k_bsum(const int* __restrict__ degc, int* __restrict__ bsum) {
    __shared__ int part[256];
    int t = threadIdx.x;
    int i = blockIdx.x * 256 + t;
    part[t] = (i < N_NODES) ? degc[i] : 0;
    __syncthreads();
#pragma unroll
    for (int off = 128; off > 0; off >>= 1) {
        if (t < off) part[t] += part[t + off];
        __syncthreads();
    }
    if (t == 0) bsum[blockIdx.x] = part[0];
}

// ---------------- phase 2: scan the 196 block sums (one tiny block) ----------------

__global__ __launch_bounds__(256) void k_scan_bsums(const int* __restrict__ bsum,
                                                    int* __restrict__ boff,
                                                    int* __restrict__ row_ptr) {
    __shared__ int part[256];
    int t = threadIdx.x;
    part[t] = (t < NB) ? bsum[t] : 0;
    __syncthreads();
    for (int off = 1; off < 256; off <<= 1) {
        int v = (t >= off) ? part[t - off] : 0;
        __syncthreads();
        part[t] += v;
        __syncthreads();
    }
    if (t < NB) boff[t] = (t == 0) ? 0 : part[t - 1];
    if (t == 0) row_ptr[N_NODES] = part[NB - 1];  // total == N_EDGES
}

// ---------------- phase 3: per-block exclusive scan + offset ----------------

__global__ __launch_bounds__(256) void k_scan_final(const int* __restrict__ degc,
                                                    const int* __restrict__ boff,
                                                    int* __restrict__ row_ptr,
                                                    int* __restrict__ cursor) {
    __shared__ int part[256];
    int t = threadIdx.x;
    int i = blockIdx.x * 256 + t;
    int v = (i < N_NODES) ? degc[i] : 0;
    part[t] = v;
    __syncthreads();
    for (int off = 1; off < 256; off <<= 1) {
        int p = (t >= off) ? part[t - off] : 0;
        __syncthreads();
        part[t] += p;
        __syncthreads();
    }
    if (i < N_NODES) {
        int val = boff[blockIdx.x] + part[t] - v;  // exclusive
        row_ptr[i] = val;
        cursor[i] = val;
    }
}

// ---------------- dinv ----------------

__global__ __launch_bounds__(256) void k_dinv(const int* __restrict__ degc, float* dinv) {
    int i = blockIdx.x * 256 + threadIdx.x;
    if (i < N_NODES) dinv[i] = rsqrtf((float)(degc[i] + 1));  // +1 self-loop
}

// ---------------- scatter edges into CSR records (src, w) ----------------

__global__ __launch_bounds__(256) void k_scatter(const int* __restrict__ src,
                                                 const int* __restrict__ dst,
                                                 const float* __restrict__ dinv,
                                                 int* __restrict__ cursor,
                                                 int2* __restrict__ rec) {
    int e = blockIdx.x * 256 + threadIdx.x;
    if (e >= N_EDGES) return;
    int s = src[e];
    int d = dst[e];
    float w = dinv[s] * dinv[d];
    int pos = atomicAdd(&cursor[d], 1);
    rec[pos] = make_int2(s, __float_as_int(w));
}

// ---------------- GEMM1: h = x @ W1 ----------------

__device__ inline void fma4(float4& acc, float s, const float4& w) {
    acc.x = fmaf(s, w.x, acc.x);
    acc.y = fmaf(s, w.y, acc.y);
    acc.z = fmaf(s, w.z, acc.z);
    acc.w = fmaf(s, w.w, acc.w);
}

__global__ __launch_bounds__(256) void k_gemm1(
    const float* __restrict__ x, const float* __restrict__ W1, float* __restrict__ h)
{
    __shared__ float Ws[D_IN * HIDDEN];  // [k][col] 32KB
    __shared__ float xs[64 * D_IN];      // [row][k^swz] 32KB
    const int tid = threadIdx.x;
    const int row0 = blockIdx.x * 64;

    const float4* W4 = (const float4*)W1;
    float4* Ws4 = (float4*)Ws;
    for (int i = tid; i < D_IN * HIDDEN / 4; i += 256) Ws4[i] = W4[i];

    for (int i = tid; i < 64 * D_IN / 4; i += 256) {
        int r = i >> 5;
        int k4 = (i & 31) << 2;
        float4 v = make_float4(0.f, 0.f, 0.f, 0.f);
        int grow = row0 + r;
        if (grow < N_NODES) v = *(const float4*)&x[grow * D_IN + k4];
        int sw = ((r >> 2) & 1) << 4;
        *(float4*)&xs[r * D_IN + (k4 ^ sw)] = v;
    }
    __syncthreads();

    const int c4 = (tid & 15) * 4;
    const int r4 = (tid >> 4) * 4;
    float4 acc[4];
#pragma unroll
    for (int j = 0; j < 4; j++) acc[j] = make_float4(0.f, 0.f, 0.f, 0.f);

    for (int k = 0; k < D_IN; k += 4) {
        float4 w0 = *(const float4*)&Ws[(k + 0) * HIDDEN + c4];
        float4 w1 = *(const float4*)&Ws[(k + 1) * HIDDEN + c4];
        float4 w2 = *(const float4*)&Ws[(k + 2) * HIDDEN + c4];
        float4 w3 = *(const float4*)&Ws[(k + 3) * HIDDEN + c4];
        float4 a[4];
#pragma unroll
        for (int j = 0; j < 4; j++) {
            int r = r4 + j;
            int sw = ((r >> 2) & 1) << 4;
            a[j] = *(const float4*)&xs[r * D_IN + (k ^ sw)];
        }
#pragma unroll
        for (int j = 0; j < 4; j++) {
            fma4(acc[j], a[j].x, w0);
            fma4(acc[j], a[j].y, w1);
            fma4(acc[j], a[j].z, w2);
            fma4(acc[j], a[j].w, w3);
        }
    }

#pragma unroll
    for (int j = 0; j < 4; j++) {
        int grow = row0 + r4 + j;
        if (grow < N_NODES) *(float4*)&h[grow * HIDDEN + c4] = acc[j];
    }
}

// ---------------- fused: pull-aggregate layer1 + relu + layer2 matmul + self-loop init ----------------
// one wave per node; lane = feature. Per edge: 8B broadcast record + 256B coalesced h-row.
__global__ __launch_bounds__(256) void k_agg1_l2(
    const float* __restrict__ h, const int* __restrict__ row_ptr,
    const int2* __restrict__ rec, const float* __restrict__ dinv,
    const float* __restrict__ b1, const float* __restrict__ W2,
    const float* __restrict__ b2, float* __restrict__ z, float* __restrict__ out)
{
    int node = blockIdx.x * 4 + (threadIdx.x >> 6);  // grid 12500, exact
    int lane = threadIdx.x & 63;

    float di = dinv[node];
    float acc = h[node * HIDDEN + lane] * (di * di);  // self-loop term

    int beg = row_ptr[node];
    int end = row_ptr[node + 1];
    int e = beg;
    // 2-edge software pipeline to keep two h-row loads in flight
    for (; e + 1 < end; e += 2) {
        int2 r0 = rec[e];
        int2 r1 = rec[e + 1];
        float v0 = h[(size_t)r0.x * HIDDEN + lane];
        float v1 = h[(size_t)r1.x * HIDDEN + lane];
        acc = fmaf(v0, __int_as_float(r0.y), acc);
        acc = fmaf(v1, __int_as_float(r1.y), acc);
    }
    if (e < end) {
        int2 r0 = rec[e];
        acc = fmaf(h[(size_t)r0.x * HIDDEN + lane], __int_as_float(r0.y), acc);
    }

    // layer 2: y = relu(acc + b1); p = y @ W2 (wave-reduce)
    float y = fmaxf(acc + b1[lane], 0.0f);
    float p0 = y * W2[lane * N_CLASSES + 0];
    float p1 = y * W2[lane * N_CLASSES + 1];
#pragma unroll
    for (int off = 32; off > 0; off >>= 1) {
        p0 += __shfl_down(p0, off, 64);
        p1 += __shfl_down(p1, off, 64);
    }
    if (lane == 0) {
        float s2 = di * di;
        z[node * 2 + 0] = p0;
        z[node * 2 + 1] = p1;
        out[node * 2 + 0] = fmaf(p0, s2, b2[0]);  // self-loop + bias init
        out[node * 2 + 1] = fmaf(p1, s2, b2[1]);
    }
}

// ---------------- pull-aggregate layer 2 (thread per node) ----------------

__global__ __launch_bounds__(256) void k_agg2(
    const float* __restrict__ z, const int* __restrict__ row_ptr,
    const int2* __restrict__ rec, float* __restrict__ out)
{
    int i = blockIdx.x * 256 + threadIdx.x;
    if (i >= N_NODES) return;
    float a0 = out[i * 2 + 0];
    float a1 = out[i * 2 + 1];
    int beg = row_ptr[i];
    int end = row_ptr[i + 1];
    for (int e = beg; e < end; e++) {
        int2 r = rec[e];
        float w = __int_as_float(r.y);
        float2 v = *(const float2*)&z[r.x * 2];
        a0 = fmaf(v.x, w, a0);
        a1 = fmaf(v.y, w, a1);
    }
    out[i * 2 + 0] = a0;
    out[i * 2 + 1] = a1;
}

// ---------------- launch ----------------

extern "C" void kernel_launch(void* const* d_in, const int* in_sizes, int n_in,
                              void* d_out, int out_size, void* d_ws, size_t ws_size,
                              hipStream_t stream) {
    const float* x  = (const float*)d_in[0];
    const int* ei   = (const int*)d_in[1];
    const float* W1 = (const float*)d_in[2];
    const float* b1 = (const float*)d_in[3];
    const float* W2 = (const float*)d_in[4];
    const float* b2 = (const float*)d_in[5];
    float* out = (float*)d_out;

    const int* src = ei;
    const int* dst = ei + N_EDGES;

    // workspace layout (4-byte units)
    int*   degc    = (int*)d_ws;                     // [0, 50176)
    float* dinv    = (float*)d_ws + NPAD;            // [50176, 100352)
    int*   row_ptr = (int*)d_ws + 2 * NPAD;          // 50001 -> pad to 150532
    int*   cursor  = (int*)d_ws + 150532;            // [150532, 200708)
    int*   bsum    = (int*)d_ws + 200708;            // 196 -> pad to 200964
    int*   boff    = (int*)d_ws + 200964;            // 196 -> pad to 201220 (16B-aligned)
    int2*  rec     = (int2*)((int*)d_ws + 201220);   // 800000 int2 = 1.6M units
    float* h       = (float*)d_ws + 1801220;         // 3.2M units (16B aligned)
    float* z       = (float*)d_ws + 5001220;         // 100k units

    hipMemsetAsync(degc, 0, NPAD * sizeof(int), stream);
    k_count_deg<<<(N_EDGES + 255) / 256, 256, 0, stream>>>(dst, degc);
    k_bsum<<<NB, 256, 0, stream>>>(degc, bsum);
    k_scan_bsums<<<1, 256, 0, stream>>>(bsum, boff, row_ptr);
    k_scan_final<<<NB, 256, 0, stream>>>(degc, boff, row_ptr, cursor);
    k_dinv<<<(N_NODES + 255) / 256, 256, 0, stream>>>(degc, dinv);
    k_scatter<<<(N_EDGES + 255) / 256, 256, 0, stream>>>(src, dst, dinv, cursor, rec);
    k_gemm1<<<(N_NODES + 63) / 64, 256, 0, stream>>>(x, W1, h);
    k_agg1_l2<<<N_NODES / 4, 256, 0, stream>>>(h, row_ptr, rec, dinv, b1, W2, b2, z, out);
    k_agg2<<<(N_NODES + 255) / 256, 256, 0, stream>>>(z, row_ptr, rec, out);
}